// Round 6
// baseline (40.370 us; speedup 1.0000x reference)
//
#include <hip/hip_runtime.h>
#include <stdint.h>

#define HT 56
#define WD 56
#define CH 16
#define FT 16
#define KK 144          // 3*3*16 patch size
#define WAVES 4         // waves per block
#define THREADS 256
#define KPW 160         // padded per-wave key stride (uint32), 16B-aligned
#define INV23 (1.0f / 8388608.0f)
#define PERM 2897u      // coprime to npix=12544 -> bijective scramble

// One wave = FOUR output pixels (16 lanes each; lane%16 = channel/feature),
// pixels scrambled by n -> (2897 n) mod npix for fallback load balance.
// 32-bit keys: t = m*2^-23 exactly (jax.random.uniform), key=(m<<8)|k; padded
// taps excluded from keys (their zeros handled analytically).
// Interior fast path: first sorted candidate = group-min key; validate exactly.
// Border fast path: candidate at end of zero block: num=0, den = alpha +
//   sum over padded taps of colsum[j] (per-block LDS table); valid iff
//   thr>=0 && den>0 && thr < t1*den  -> output thr/den (=0 for thr=0).
// Any data-zero, or any feature failing validation -> verified whole-wave
// sort+scan fallback for that pixel.
__global__ __launch_bounds__(THREADS) void spiking_conv2d_kernel(
    const float* __restrict__ tj,        // [B,56,56,16]
    const float* __restrict__ kern,      // [3,3,16,16] flat [144][16]
    const float* __restrict__ threshold, // [16]
    const float* __restrict__ alpha,     // [16]
    float* __restrict__ out,             // [B,56,56,16]
    int npix)
{
    __shared__ float    sCol[9][FT];        // channel-sums per (tap, feature)
    __shared__ uint32_t sKey[WAVES][KPW];   // fallback keys, 2560 B

    const int tid  = threadIdx.x;
    const int wave = tid >> 6;
    const int lane = tid & 63;
    const int g    = lane >> 4;             // pixel subgroup 0..3
    const int l    = lane & 15;             // channel / feature

    // ---- per-block colsum table: sCol[j][f] = sum_c kern[j,c,f] -------------
    if (tid < 144) {
        const int j = tid >> 4, f = tid & 15;
        float s = 0.0f;
        #pragma unroll
        for (int c = 0; c < 16; ++c) s += kern[(j * 16 + c) * FT + f];
        sCol[j][f] = s;
    }
    __syncthreads();

    const int NW  = (npix + 3) >> 2;        // total waves (=3136)
    const int wid = blockIdx.x * WAVES + wave;
    if (wid >= NW) return;

    const int n0    = wid + g * NW;
    const bool pixOK = (n0 < npix);
    const int n = pixOK ? (int)((PERM * (uint32_t)n0) % (uint32_t)npix) : 0;

    const int hw  = HT * WD;
    const int bb  = n / hw;
    const int rem = n - bb * hw;
    const int y   = rem / WD;
    const int x   = rem - y * WD;

    // ---- load real taps, build keys, local two-min; pad/zero detection ------
    uint32_t m1 = 0xFFFFFFFFu, m2 = 0xFFFFFFFFu;
    bool dataZero = false;
    int  padmask  = 0;
    #pragma unroll
    for (int j = 0; j < 9; ++j) {
        const int di = j / 3, dj = j - 3 * di;
        const int yy = y + di - 1;          // 'same' pad
        const int xx = x + dj - 1;
        if ((unsigned)yy < (unsigned)HT && (unsigned)xx < (unsigned)WD) {
            const float t = tj[(((bb * HT) + yy) * WD + xx) * CH + l];
            const uint32_t m = (uint32_t)(t * 8388608.0f);   // exact
            dataZero |= (m == 0u);
            const uint32_t key = (m << 8) | (uint32_t)(j * 16 + l);
            const uint32_t lo = min(key, m1);
            const uint32_t hi = max(key, m1);
            m1 = lo;
            m2 = min(m2, hi);
        } else {
            padmask |= (1 << j);            // group-uniform
        }
    }
    // 16-lane group two-min reduce (xor 1,2,4,8 stays inside the group)
    #pragma unroll
    for (int s = 1; s < 16; s <<= 1) {
        const uint32_t o1 = (uint32_t)__shfl_xor((int)m1, s);
        const uint32_t o2 = (uint32_t)__shfl_xor((int)m2, s);
        const uint32_t nl = min(m1, o1);
        const uint32_t nh = max(m1, o1);
        m1 = nl;
        m2 = min(min(m2, o2), nh);
    }

    const unsigned long long bz = __ballot(dataZero && pixOK);
    const uint32_t zg = (uint32_t)((bz >> (g * 16)) & 0xFFFFull);

    const float thr = threshold[l];
    const float al  = alpha[l];
    const float t1  = (float)(m1 >> 8) * INV23;   // first real (nonzero) t

    bool  okl;
    float selNum, selDen;
    if (padmask == 0) {
        // interior: candidate at sorted position 0 (= min key)
        const float t2 = (float)(m2 >> 8) * INV23;
        const float w  = kern[(m1 & 255u) * FT + l];  // group-uniform row
        selNum = fmaf(w, t1, thr);                    // + alpha*T_MIN_PREV (=0)
        selDen = w + al;
        okl = (zg == 0u) && (selDen > 0.0f) && (selNum < t2 * selDen);
    } else {
        // border: candidate at end of the (padding-)zero block
        float dz = al;
        #pragma unroll
        for (int j = 0; j < 9; ++j)
            if (padmask & (1 << j)) dz += sCol[j][l];
        selNum = thr;
        selDen = dz;
        okl = (zg == 0u) && (thr >= 0.0f) && (dz > 0.0f) && (thr < t1 * dz);
    }

    const unsigned long long bok = __ballot(okl || !pixOK);
    const bool groupFast =
        (((uint32_t)((bok >> (g * 16)) & 0xFFFFull)) == 0xFFFFu);
    if (groupFast && pixOK) {
        const float ti = selNum / selDen;
        out[n * FT + l] = (ti < 1.0f) ? ti : 1.0f;    // clamp to T_MAX
    }

    // ---- fallback mask (wave-uniform) ---------------------------------------
    uint32_t fbmask = 0;
    #pragma unroll
    for (int gg = 0; gg < 4; ++gg) {
        const uint32_t okgg = (uint32_t)((bok >> (gg * 16)) & 0xFFFFull);
        if (okgg != 0xFFFFu && (wid + gg * NW) < npix) fbmask |= (1u << gg);
    }
    if (fbmask == 0) return;

    // ==================== whole-wave fallback per failing pixel ==============
    while (fbmask) {
        const int gg = __builtin_ctz(fbmask);
        fbmask &= fbmask - 1;
        const int pn0 = wid + gg * NW;
        const int pn  = (int)((PERM * (uint32_t)pn0) % (uint32_t)npix);

        const int bb2  = pn / hw;
        const int rem2 = pn - bb2 * hw;
        const int y2   = rem2 / WD;
        const int x2   = rem2 - y2 * WD;

        auto makeKey = [&](int k) -> uint32_t {
            const int tap = k >> 4;
            const int ch  = k & 15;
            const int di  = tap / 3;
            const int dj  = tap - 3 * di;
            const int yy  = y2 + di - 1;
            const int xx  = x2 + dj - 1;
            float t = 0.0f;
            if ((unsigned)yy < (unsigned)HT && (unsigned)xx < (unsigned)WD)
                t = tj[(((bb2 * HT) + yy) * WD + xx) * CH + ch];
            const uint32_t m = (uint32_t)(t * 8388608.0f);
            return (m << 8) | (uint32_t)k;
        };

        const uint32_t key0 = makeKey(lane);
        const uint32_t key1 = makeKey(lane + 64);
        const uint32_t key2 = (lane < 16) ? makeKey(lane + 128) : 0xFFFFFFFFu;

        sKey[wave][lane]      = key0;
        sKey[wave][lane + 64] = key1;
        if (lane < 16) sKey[wave][lane + 128] = key2;

        int r0 = 0, r1 = 0, r2 = 0;
        {
            const uint4* kp = (const uint4*)(&sKey[wave][0]);
            #pragma unroll 6
            for (int jj = 0; jj < KK / 4; ++jj) {
                const uint4 kj = kp[jj];     // broadcast b128 read
                r0 += (kj.x < key0) + (kj.y < key0) + (kj.z < key0) + (kj.w < key0);
                r1 += (kj.x < key1) + (kj.y < key1) + (kj.z < key1) + (kj.w < key1);
                r2 += (kj.x < key2) + (kj.y < key2) + (kj.z < key2) + (kj.w < key2);
            }
        }
        sKey[wave][r0] = key0;               // in-place scatter; same-wave DS in order
        sKey[wave][r1] = key1;
        if (lane < 16) sKey[wave][r2] = key2;

        // pass A: per-chunk partial sums (chunk = g, feature = l)
        float lN = 0.0f, lD = 0.0f;
        {
            const uint4* kq4 = (const uint4*)(&sKey[wave][0]) + g * 9;
            #pragma unroll
            for (int jj = 0; jj < 9; ++jj) {
                const uint4 kq = kq4[jj];
                const uint32_t ks[4] = {kq.x, kq.y, kq.z, kq.w};
                #pragma unroll
                for (int e = 0; e < 4; ++e) {
                    const uint32_t kk = ks[e];
                    const float t  = (float)(kk >> 8) * INV23;
                    const float ww = kern[(kk & 255u) * FT + l];
                    lN = fmaf(ww, t, lN);
                    lD += ww;
                }
            }
        }
        float iN = lN, iD = lD;
        {
            float sN = __shfl_up(iN, 16), sD = __shfl_up(iD, 16);
            if (g >= 1) { iN += sN; iD += sD; }
            sN = __shfl_up(iN, 32); sD = __shfl_up(iD, 32);
            if (g >= 2) { iN += sN; iD += sD; }
        }
        float num = iN - lN;    // exclusive prefix of cumsum(J*t)
        float den = iD - lD;    // exclusive prefix of cumsum(J)

        const int kbeg = g * 36;
        uint32_t ecur = sKey[wave][kbeg];
        float tbound = __shfl_down((float)(ecur >> 8) * INV23, 16);
        if (g == 3) tbound = 1.0e6f;

        float sN2 = 0.0f, sD2 = 1.0f;
        bool  found = false;
        #pragma unroll 4
        for (int i = 0; i < 36; ++i) {
            uint32_t enext = 0; float tn;
            if (i < 35) { enext = sKey[wave][kbeg + i + 1]; tn = (float)(enext >> 8) * INV23; }
            else        { tn = tbound; }
            const float t  = (float)(ecur >> 8) * INV23;
            const float ww = kern[(ecur & 255u) * FT + l];
            num = fmaf(ww, t, num);
            den += ww;
            const float numt2 = num + thr;
            const float dena2 = den + al;
            const bool valid = (dena2 > 0.0f) && (numt2 < tn * dena2);
            const bool take  = !found && (valid || (g == 0 && i == 0));
            if (take) { sN2 = numt2; sD2 = dena2; }
            found = found || valid;
            if (i < 35) ecur = enext;
        }
        int pos = found ? g : ((g == 0) ? 6 : 7);
        {
            int   opos = __shfl_xor(pos, 16);
            float oN   = __shfl_xor(sN2, 16);
            float oD   = __shfl_xor(sD2, 16);
            if (opos < pos) { pos = opos; sN2 = oN; sD2 = oD; }
            opos = __shfl_xor(pos, 32);
            oN   = __shfl_xor(sN2, 32);
            oD   = __shfl_xor(sD2, 32);
            if (opos < pos) { pos = opos; sN2 = oN; sD2 = oD; }
        }
        if (g == 0) {
            const float ti = sN2 / sD2;
            out[pn * FT + l] = (ti < 1.0f) ? ti : 1.0f;
        }
    }
}

extern "C" void kernel_launch(void* const* d_in, const int* in_sizes, int n_in,
                              void* d_out, int out_size, void* d_ws, size_t ws_size,
                              hipStream_t stream) {
    const float* tj    = (const float*)d_in[0];
    const float* kern  = (const float*)d_in[1];
    const float* thr   = (const float*)d_in[2];
    const float* alpha = (const float*)d_in[3];
    float*       out   = (float*)d_out;

    const int npix   = in_sizes[0] / CH;                 // B*H*W = 12544
    const int NW     = (npix + 3) >> 2;                  // waves = 3136
    const int blocks = (NW + WAVES - 1) / WAVES;         // 784
    spiking_conv2d_kernel<<<blocks, THREADS, 0, stream>>>(tj, kern, thr, alpha, out, npix);
}

// Round 7
// 32.740 us; speedup vs baseline: 1.2330x; 1.2330x over previous
//
#include <hip/hip_runtime.h>
#include <stdint.h>

#define HT 56
#define WD 56
#define CH 16
#define FT 16
#define KK 144          // 3*3*16 patch size
#define WAVES 16        // waves per block = pixels per block
#define THREADS 1024
#define KPW 160         // padded per-wave key stride (uint32), 16B-aligned
#define INV23 (1.0f / 8388608.0f)

// One wave = ONE output pixel (consecutive order, coalesced).
// 32-bit keys: t = m*2^-23 exactly (jax.random.uniform), key=(m<<8)|k; padded
// taps excluded (handled analytically).
// Interior fast path: first sorted candidate = global-min key; validate exactly.
// Border fast path: candidate at end of zero block: num=0, den = alpha +
//   sum over padded taps of colsum[j][f]; valid iff thr>=0 && den>0 && thr<t1*den.
// Any data-zero or failed validation -> verified whole-wave sort+scan fallback.
__global__ __launch_bounds__(THREADS) void spiking_conv2d_kernel(
    const float* __restrict__ tj,        // [B,56,56,16]
    const float* __restrict__ kern,      // [3,3,16,16] flat [144][16]
    const float* __restrict__ threshold, // [16]
    const float* __restrict__ alpha,     // [16]
    float* __restrict__ out,             // [B,56,56,16]
    int npix)
{
    __shared__ float    sCol[9][FT];        // 576 B: colsum per (tap, feature)
    __shared__ uint32_t sKey[WAVES][KPW];   // 10240 B: fallback keys

    const int tid  = threadIdx.x;
    const int wave = tid >> 6;
    const int lane = tid & 63;

    // ---- per-block colsum table: sCol[j][f] = sum_c kern[j,c,f] -------------
    if (tid < 144) {
        const int j = tid >> 4, f = tid & 15;
        float s = 0.0f;
        #pragma unroll
        for (int c = 0; c < 16; ++c) s += kern[(j * 16 + c) * FT + f];
        sCol[j][f] = s;
    }
    __syncthreads();

    const int n = blockIdx.x * WAVES + wave;    // pixel id (consecutive)
    if (n >= npix) return;

    const int hw  = HT * WD;
    const int bb  = n / hw;
    const int rem = n - bb * hw;
    const int y   = rem / WD;
    const int x   = rem - y * WD;

    auto makeKey = [&](int k) -> uint32_t {
        const int tap = k >> 4;
        const int ch  = k & 15;
        const int di  = tap / 3;
        const int dj  = tap - 3 * di;
        const int yy  = y + di - 1;             // 'same' pad
        const int xx  = x + dj - 1;
        float t = 0.0f;                         // T_MIN pad
        if ((unsigned)yy < (unsigned)HT && (unsigned)xx < (unsigned)WD)
            t = tj[(((bb * HT) + yy) * WD + xx) * CH + ch];
        const uint32_t m = (uint32_t)(t * 8388608.0f);   // exact
        return (m << 8) | (uint32_t)k;
    };

    // padmask is pixel-uniform: which of the 9 taps fall in the pad region
    int padmask = 0;
    {
        #pragma unroll
        for (int j = 0; j < 9; ++j) {
            const int di = j / 3, dj = j - 3 * di;
            const int yy = y + di - 1, xx = x + dj - 1;
            if (!((unsigned)yy < (unsigned)HT && (unsigned)xx < (unsigned)WD))
                padmask |= (1 << j);
        }
    }

    const uint32_t key0 = makeKey(lane);
    const uint32_t key1 = makeKey(lane + 64);
    const uint32_t key2 = (lane < 16) ? makeKey(lane + 128) : 0xFFFFFFFFu;

    // mask out padded-tap (t==0) keys for the min-reduce; track real data zeros
    const int tap0 = lane >> 4, tap1 = (lane + 64) >> 4, tap2 = 8;
    const bool pad0 = (padmask >> tap0) & 1;
    const bool pad1 = (padmask >> tap1) & 1;
    const bool pad2 = (padmask >> tap2) & 1;
    const bool dataZero = (!pad0 && (key0 >> 8) == 0) ||
                          (!pad1 && (key1 >> 8) == 0) ||
                          (lane < 16 && !pad2 && (key2 >> 8) == 0);

    uint32_t a  = pad0 ? 0xFFFFFFFFu : key0;
    uint32_t b  = pad1 ? 0xFFFFFFFFu : key1;
    uint32_t c2 = (lane < 16 && !pad2) ? key2 : 0xFFFFFFFFu;

    // local two-min, then 6-step wave two-min reduce
    uint32_t lo = min(a, b), hi = max(a, b);
    uint32_t m1 = min(lo, c2);
    uint32_t m2 = min(hi, max(lo, c2));
    #pragma unroll
    for (int s = 1; s < 64; s <<= 1) {
        const uint32_t o1 = (uint32_t)__shfl_xor((int)m1, s);
        const uint32_t o2 = (uint32_t)__shfl_xor((int)m2, s);
        const uint32_t nl = min(m1, o1);
        const uint32_t nh = max(m1, o1);
        m2 = min(min(nh, m2), o2);
        m1 = nl;
    }

    const bool anyZero = __any(dataZero);

    const int   f   = lane & 15;
    const float thr = threshold[f];
    const float al  = alpha[f];
    const float t1  = (float)(m1 >> 8) * INV23;   // first real (nonzero) t

    bool  okl;
    float selNum, selDen;
    if (padmask == 0) {
        // interior: candidate at sorted position 0 (= min key)
        const float t2 = (float)(m2 >> 8) * INV23;
        const float w  = kern[(m1 & 255u) * FT + f];  // wave-uniform row
        selNum = fmaf(w, t1, thr);                    // + alpha*T_MIN_PREV (=0)
        selDen = w + al;
        okl = !anyZero && (selDen > 0.0f) && (selNum < t2 * selDen);
    } else {
        // border: candidate at end of the padding-zero block
        float dz = al;
        #pragma unroll
        for (int j = 0; j < 9; ++j)
            if (padmask & (1 << j)) dz += sCol[j][f];
        selNum = thr;
        selDen = dz;
        okl = !anyZero && (thr >= 0.0f) && (dz > 0.0f) && (thr < t1 * dz);
    }

    if (__all(okl)) {
        if (lane < 16) {
            const float ti = selNum / selDen;
            out[n * FT + f] = (ti < 1.0f) ? ti : 1.0f;   // clamp to T_MAX
        }
        return;
    }

    // ==================== fallback: full sort + scan (verified path) =========
    sKey[wave][lane]      = key0;
    sKey[wave][lane + 64] = key1;
    if (lane < 16) sKey[wave][lane + 128] = key2;

    int r0 = 0, r1 = 0, r2 = 0;
    {
        const uint4* kp = (const uint4*)(&sKey[wave][0]);
        #pragma unroll 6
        for (int jj = 0; jj < KK / 4; ++jj) {
            const uint4 kj = kp[jj];         // broadcast b128 read
            r0 += (kj.x < key0) + (kj.y < key0) + (kj.z < key0) + (kj.w < key0);
            r1 += (kj.x < key1) + (kj.y < key1) + (kj.z < key1) + (kj.w < key1);
            r2 += (kj.x < key2) + (kj.y < key2) + (kj.z < key2) + (kj.w < key2);
        }
    }
    sKey[wave][r0] = key0;       // in-place scatter; same-wave DS ops stay in order
    sKey[wave][r1] = key1;
    if (lane < 16) sKey[wave][r2] = key2;

    const int c = lane >> 4;     // chunk index

    // pass A: per-chunk partial sums
    float lN = 0.0f, lD = 0.0f;
    {
        const uint4* kq4 = (const uint4*)(&sKey[wave][0]) + c * 9;
        #pragma unroll
        for (int jj = 0; jj < 9; ++jj) {
            const uint4 kq = kq4[jj];
            const uint32_t ks[4] = {kq.x, kq.y, kq.z, kq.w};
            #pragma unroll
            for (int e = 0; e < 4; ++e) {
                const uint32_t kk = ks[e];
                const float t  = (float)(kk >> 8) * INV23;
                const float ww = kern[(kk & 255u) * FT + f];
                lN = fmaf(ww, t, lN);
                lD += ww;
            }
        }
    }
    float iN = lN, iD = lD;
    {
        float sN = __shfl_up(iN, 16), sD = __shfl_up(iD, 16);
        if (c >= 1) { iN += sN; iD += sD; }
        sN = __shfl_up(iN, 32); sD = __shfl_up(iD, 32);
        if (c >= 2) { iN += sN; iD += sD; }
    }
    float num = iN - lN;    // exclusive prefix of cumsum(J*t)
    float den = iD - lD;    // exclusive prefix of cumsum(J)

    const int kbeg = c * 36;
    uint32_t ecur = sKey[wave][kbeg];
    float tbound = __shfl_down((float)(ecur >> 8) * INV23, 16);
    if (c == 3) tbound = 1.0e6f;

    float sN2 = 0.0f, sD2 = 1.0f;
    bool  found = false;
    #pragma unroll 4
    for (int i = 0; i < 36; ++i) {
        uint32_t enext = 0; float tn;
        if (i < 35) { enext = sKey[wave][kbeg + i + 1]; tn = (float)(enext >> 8) * INV23; }
        else        { tn = tbound; }
        const float t  = (float)(ecur >> 8) * INV23;
        const float ww = kern[(ecur & 255u) * FT + f];
        num = fmaf(ww, t, num);
        den += ww;
        const float numt2 = num + thr;
        const float dena2 = den + al;
        const bool valid = (dena2 > 0.0f) && (numt2 < tn * dena2);
        const bool take  = !found && (valid || (c == 0 && i == 0));
        if (take) { sN2 = numt2; sD2 = dena2; }
        found = found || valid;
        if (i < 35) ecur = enext;
    }
    int pos = found ? c : ((c == 0) ? 6 : 7);
    {
        int   opos = __shfl_xor(pos, 16);
        float oN   = __shfl_xor(sN2, 16);
        float oD   = __shfl_xor(sD2, 16);
        if (opos < pos) { pos = opos; sN2 = oN; sD2 = oD; }
        opos = __shfl_xor(pos, 32);
        oN   = __shfl_xor(sN2, 32);
        oD   = __shfl_xor(sD2, 32);
        if (opos < pos) { pos = opos; sN2 = oN; sD2 = oD; }
    }
    if (c == 0) {
        const float ti = sN2 / sD2;
        out[n * FT + f] = (ti < 1.0f) ? ti : 1.0f;
    }
}

extern "C" void kernel_launch(void* const* d_in, const int* in_sizes, int n_in,
                              void* d_out, int out_size, void* d_ws, size_t ws_size,
                              hipStream_t stream) {
    const float* tj    = (const float*)d_in[0];
    const float* kern  = (const float*)d_in[1];
    const float* thr   = (const float*)d_in[2];
    const float* alpha = (const float*)d_in[3];
    float*       out   = (float*)d_out;

    const int npix   = in_sizes[0] / CH;                  // B*H*W = 12544
    const int blocks = (npix + WAVES - 1) / WAVES;        // 784
    spiking_conv2d_kernel<<<blocks, THREADS, 0, stream>>>(tj, kern, thr, alpha, out, npix);
}

// Round 8
// 31.425 us; speedup vs baseline: 1.2846x; 1.0418x over previous
//
#include <hip/hip_runtime.h>
#include <stdint.h>

#define HT 56
#define WD 56
#define CH 16
#define FT 16
#define KK 144          // 3*3*16 patch size
#define WAVES 4         // waves per block
#define THREADS 256
#define NBLOCKS 1024    // grid-stride: 4096 waves, ~3 pixels each
#define KPW 160         // padded per-wave key stride (uint32), 16B-aligned
#define INV23 (1.0f / 8388608.0f)

// One wave = one pixel per loop iteration (grid-stride over pixels, stride
// 4096 de-clusters border rows). 32-bit keys: t = m*2^-23 exactly
// (jax.random.uniform), key = (m<<8)|k -> u32 order == stable argsort.
// Software pipeline: next pixel's 3 taps/lane are issued before the current
// pixel's shfl-reduce, hiding load latency under the cross-lane chain.
// Fast path z==0: first sorted candidate = wave-min key, validated exactly.
// Fast path z>0: candidate at end of zero block (num=0, den from zero-entry
// weight sum), validated exactly. Failures -> verified whole-wave sort+scan.
__global__ __launch_bounds__(THREADS) void spiking_conv2d_kernel(
    const float* __restrict__ tj,        // [B,56,56,16]
    const float* __restrict__ kern,      // [3,3,16,16] flat [144][16]
    const float* __restrict__ threshold, // [16]
    const float* __restrict__ alpha,     // [16]
    float* __restrict__ out,             // [B,56,56,16]
    int npix)
{
    __shared__ uint32_t sKey[WAVES][KPW];   // 2560 B

    const int tid  = threadIdx.x;
    const int wave = tid >> 6;
    const int lane = tid & 63;
    const int f    = lane & 15;             // channel / feature
    const int cch  = lane >> 4;             // tap-group / chunk index

    const float thr = threshold[f];
    const float al  = alpha[f];

    const int gw     = blockIdx.x * WAVES + wave;   // global wave id
    const int nwaves = gridDim.x * WAVES;           // 4096
    const int hw     = HT * WD;

    // lane's tap indices: k0 = lane (tap cch), k1 = lane+64 (tap cch+4),
    // k2 = lane+128 (tap 8, lane<16 only); channel is always f.
    auto tapLoad = [&](int tap, int y, int x, int base) -> float {
        const int di = tap / 3, dj = tap - 3 * di;
        const int yy = y + di - 1;              // 'same' pad
        const int xx = x + dj - 1;
        float t = 0.0f;                         // T_MIN pad
        if ((unsigned)yy < (unsigned)HT && (unsigned)xx < (unsigned)WD)
            t = tj[base + (yy * WD + xx) * CH + f];
        return t;
    };
    auto issue3 = [&](int pp, float& a, float& b, float& c) {
        const int bb  = pp / hw;
        const int rem = pp - bb * hw;
        const int y   = rem / WD;
        const int x   = rem - y * WD;
        const int base = bb * hw * CH;
        a = tapLoad(cch, y, x, base);
        b = tapLoad(cch + 4, y, x, base);
        c = (lane < 16) ? tapLoad(8, y, x, base) : 0.0f;
    };

    int   p = gw;
    float ta = 0.0f, tb = 0.0f, tcv = 0.0f;
    if (p < npix) issue3(p, ta, tb, tcv);

    while (p < npix) {
        // ---- keys for current pixel ----------------------------------------
        const uint32_t ma = (uint32_t)(ta * 8388608.0f);    // exact
        const uint32_t mb = (uint32_t)(tb * 8388608.0f);
        const uint32_t mc = (uint32_t)(tcv * 8388608.0f);
        const uint32_t key0 = (ma << 8) | (uint32_t)lane;
        const uint32_t key1 = (mb << 8) | (uint32_t)(lane + 64);
        const uint32_t key2 = (lane < 16) ? ((mc << 8) | (uint32_t)(lane + 128))
                                          : 0xFFFFFFFFu;

        // ---- prefetch next pixel (overlaps reduce below) -------------------
        const int pn = p + nwaves;
        float ua = 0.0f, ub = 0.0f, uc = 0.0f;
        if (pn < npix) issue3(pn, ua, ub, uc);

        // ---- zero census + two-min reduce (zeros masked out) ---------------
        const bool isz0 = (key0 >> 8) == 0;
        const bool isz1 = (key1 >> 8) == 0;
        const bool isz2 = (lane < 16) && ((key2 >> 8) == 0);
        const int z = __popcll(__ballot(isz0)) + __popcll(__ballot(isz1))
                    + __popcll(__ballot(isz2));

        uint32_t a  = isz0 ? 0xFFFFFFFFu : key0;
        uint32_t b  = isz1 ? 0xFFFFFFFFu : key1;
        uint32_t c2 = (lane < 16 && !isz2) ? key2 : 0xFFFFFFFFu;
        uint32_t lo = min(a, b), hi = max(a, b);
        uint32_t m1 = min(lo, c2);
        uint32_t m2 = min(hi, max(lo, c2));
        #pragma unroll
        for (int s = 1; s < 64; s <<= 1) {
            const uint32_t o1 = (uint32_t)__shfl_xor((int)m1, s);
            const uint32_t o2 = (uint32_t)__shfl_xor((int)m2, s);
            const uint32_t nl = min(m1, o1);
            const uint32_t nh = max(m1, o1);
            m2 = min(min(nh, m2), o2);
            m1 = nl;
        }

        bool  fastOk;
        float selN, selD;
        if (z == 0) {
            // interior: candidate at sorted position 0 (= wave-min key)
            const float t1 = (float)(m1 >> 8) * INV23;
            const float t2 = (float)(m2 >> 8) * INV23;
            const float w  = kern[(m1 & 255u) * FT + f];   // wave-uniform row
            selN = fmaf(w, t1, thr);                       // + alpha*T_MIN_PREV (=0)
            selD = w + al;
            fastOk = (selD > 0.0f) && (selN < t2 * selD);
        } else {
            // border/zero: candidate at end of zero block (num = 0 exactly)
            sKey[wave][lane]      = key0;
            sKey[wave][lane + 64] = key1;
            if (lane < 16) sKey[wave][lane + 128] = key2;
            float wsum = 0.0f;
            const uint4* kp = (const uint4*)(&sKey[wave][0]) + cch * 9;
            #pragma unroll
            for (int j = 0; j < 9; ++j) {
                const uint4 kq = kp[j];
                const uint32_t ks[4] = {kq.x, kq.y, kq.z, kq.w};
                #pragma unroll
                for (int e = 0; e < 4; ++e)
                    if ((ks[e] >> 8) == 0) wsum += kern[(ks[e] & 255u) * FT + f];
            }
            wsum += __shfl_xor(wsum, 16);
            wsum += __shfl_xor(wsum, 32);
            const float dena = wsum + al;
            const float tz   = (float)(m1 >> 8) * INV23;   // first nonzero t
            fastOk = (thr >= 0.0f) && (dena > 0.0f) && (thr < tz * dena);
            selN = thr; selD = dena;
        }

        if (__all(fastOk)) {
            if (lane < 16) {
                const float ti = selN / selD;
                out[p * FT + f] = (ti < 1.0f) ? ti : 1.0f;   // clamp to T_MAX
            }
        } else {
            // ================= verified full sort + scan fallback ===========
            sKey[wave][lane]      = key0;
            sKey[wave][lane + 64] = key1;
            if (lane < 16) sKey[wave][lane + 128] = key2;

            int r0 = 0, r1 = 0, r2 = 0;
            {
                const uint4* kp = (const uint4*)(&sKey[wave][0]);
                #pragma unroll 6
                for (int jj = 0; jj < KK / 4; ++jj) {
                    const uint4 kj = kp[jj];     // broadcast b128 read
                    r0 += (kj.x < key0) + (kj.y < key0) + (kj.z < key0) + (kj.w < key0);
                    r1 += (kj.x < key1) + (kj.y < key1) + (kj.z < key1) + (kj.w < key1);
                    r2 += (kj.x < key2) + (kj.y < key2) + (kj.z < key2) + (kj.w < key2);
                }
            }
            sKey[wave][r0] = key0;   // in-place scatter; same-wave DS in order
            sKey[wave][r1] = key1;
            if (lane < 16) sKey[wave][r2] = key2;

            // pass A: per-chunk partial sums over sorted keys
            float lN = 0.0f, lD = 0.0f;
            {
                const uint4* kq4 = (const uint4*)(&sKey[wave][0]) + cch * 9;
                #pragma unroll
                for (int jj = 0; jj < 9; ++jj) {
                    const uint4 kq = kq4[jj];
                    const uint32_t ks[4] = {kq.x, kq.y, kq.z, kq.w};
                    #pragma unroll
                    for (int e = 0; e < 4; ++e) {
                        const uint32_t kk = ks[e];
                        const float t  = (float)(kk >> 8) * INV23;
                        const float ww = kern[(kk & 255u) * FT + f];
                        lN = fmaf(ww, t, lN);
                        lD += ww;
                    }
                }
            }
            float iN = lN, iD = lD;
            {
                float sN = __shfl_up(iN, 16), sD = __shfl_up(iD, 16);
                if (cch >= 1) { iN += sN; iD += sD; }
                sN = __shfl_up(iN, 32); sD = __shfl_up(iD, 32);
                if (cch >= 2) { iN += sN; iD += sD; }
            }
            float num = iN - lN;    // exclusive prefix of cumsum(J*t)
            float den = iD - lD;    // exclusive prefix of cumsum(J)

            const int kbeg = cch * 36;
            uint32_t ecur = sKey[wave][kbeg];
            float tbound = __shfl_down((float)(ecur >> 8) * INV23, 16);
            if (cch == 3) tbound = 1.0e6f;

            float sN2 = 0.0f, sD2 = 1.0f;
            bool  found = false;
            #pragma unroll 4
            for (int i = 0; i < 36; ++i) {
                uint32_t enext = 0; float tn;
                if (i < 35) { enext = sKey[wave][kbeg + i + 1]; tn = (float)(enext >> 8) * INV23; }
                else        { tn = tbound; }
                const float t  = (float)(ecur >> 8) * INV23;
                const float ww = kern[(ecur & 255u) * FT + f];
                num = fmaf(ww, t, num);
                den += ww;
                const float numt2 = num + thr;
                const float dena2 = den + al;
                const bool valid = (dena2 > 0.0f) && (numt2 < tn * dena2);
                const bool take  = !found && (valid || (cch == 0 && i == 0));
                if (take) { sN2 = numt2; sD2 = dena2; }
                found = found || valid;
                if (i < 35) ecur = enext;
            }
            int pos = found ? cch : ((cch == 0) ? 6 : 7);
            {
                int   opos = __shfl_xor(pos, 16);
                float oN   = __shfl_xor(sN2, 16);
                float oD   = __shfl_xor(sD2, 16);
                if (opos < pos) { pos = opos; sN2 = oN; sD2 = oD; }
                opos = __shfl_xor(pos, 32);
                oN   = __shfl_xor(sN2, 32);
                oD   = __shfl_xor(sD2, 32);
                if (opos < pos) { pos = opos; sN2 = oN; sD2 = oD; }
            }
            if (cch == 0) {
                const float ti = sN2 / sD2;
                out[p * FT + f] = (ti < 1.0f) ? ti : 1.0f;
            }
        }

        p  = pn;
        ta = ua; tb = ub; tcv = uc;
    }
}

extern "C" void kernel_launch(void* const* d_in, const int* in_sizes, int n_in,
                              void* d_out, int out_size, void* d_ws, size_t ws_size,
                              hipStream_t stream) {
    const float* tj    = (const float*)d_in[0];
    const float* kern  = (const float*)d_in[1];
    const float* thr   = (const float*)d_in[2];
    const float* alpha = (const float*)d_in[3];
    float*       out   = (float*)d_out;

    const int npix = in_sizes[0] / CH;                   // B*H*W = 12544
    spiking_conv2d_kernel<<<NBLOCKS, THREADS, 0, stream>>>(tj, kern, thr, alpha, out, npix);
}

// Round 9
// 25.694 us; speedup vs baseline: 1.5712x; 1.2231x over previous
//
#include <hip/hip_runtime.h>
#include <stdint.h>

#define HT 56
#define WD 56
#define CH 16
#define FT 16
#define KK 144          // 3*3*16 patch size
#define WAVES 4         // waves per block = pixels per block
#define THREADS 256
#define KPW 160         // padded per-wave key stride (uint32), 16B-aligned
#define INV23 (1.0f / 8388608.0f)

// Cold path: verified full rank-sort + prefix-scan + first-valid select.
// noinline + de-unrolled so its code lives off the hot I-fetch path.
__device__ __attribute__((noinline))
void cold_pixel(const float* __restrict__ tj, const float* __restrict__ kern,
                float thr, float al, float* __restrict__ out,
                int n, uint32_t* __restrict__ skey)
{
    const int lane = (int)(threadIdx.x & 63);
    const int f = lane & 15;
    const int c = lane >> 4;
    const int hw  = HT * WD;
    const int bb  = n / hw;
    const int rem = n - bb * hw;
    const int y   = rem / WD;
    const int x   = rem - y * WD;

    auto makeKey = [&](int k) -> uint32_t {
        const int tap = k >> 4;
        const int ch  = k & 15;
        const int di  = tap / 3;
        const int dj  = tap - 3 * di;
        const int yy  = y + di - 1;             // 'same' pad
        const int xx  = x + dj - 1;
        float t = 0.0f;                         // T_MIN pad
        if ((unsigned)yy < (unsigned)HT && (unsigned)xx < (unsigned)WD)
            t = tj[(bb * hw + yy * WD + xx) * CH + ch];
        const uint32_t m = (uint32_t)(t * 8388608.0f);   // exact
        return (m << 8) | (uint32_t)k;
    };

    const uint32_t key0 = makeKey(lane);
    const uint32_t key1 = makeKey(lane + 64);
    const uint32_t key2 = (lane < 16) ? makeKey(lane + 128) : 0xFFFFFFFFu;

    skey[lane]      = key0;
    skey[lane + 64] = key1;
    if (lane < 16) skey[lane + 128] = key2;

    // rank = count of strictly-smaller keys (keys unique: low 8 bits = k)
    int r0 = 0, r1 = 0, r2 = 0;
    {
        const uint4* kp = (const uint4*)skey;
        #pragma unroll 1
        for (int j = 0; j < KK / 4; ++j) {
            const uint4 kj = kp[j];             // broadcast b128 read
            r0 += (kj.x < key0) + (kj.y < key0) + (kj.z < key0) + (kj.w < key0);
            r1 += (kj.x < key1) + (kj.y < key1) + (kj.z < key1) + (kj.w < key1);
            r2 += (kj.x < key2) + (kj.y < key2) + (kj.z < key2) + (kj.w < key2);
        }
    }
    skey[r0] = key0;        // in-place scatter; same-wave DS ops stay in order
    skey[r1] = key1;
    if (lane < 16) skey[r2] = key2;

    // pass A: per-chunk partial sums over sorted keys
    float lN = 0.0f, lD = 0.0f;
    {
        const uint4* kq4 = (const uint4*)skey + c * 9;
        #pragma unroll 1
        for (int j = 0; j < 9; ++j) {
            const uint4 kq = kq4[j];
            const uint32_t ks[4] = {kq.x, kq.y, kq.z, kq.w};
            #pragma unroll
            for (int e = 0; e < 4; ++e) {
                const uint32_t kk = ks[e];
                const float t = (float)(kk >> 8) * INV23;
                const float w = kern[(kk & 255u) * FT + f];
                lN = fmaf(w, t, lN);
                lD += w;
            }
        }
    }
    float iN = lN, iD = lD;
    {
        float sN = __shfl_up(iN, 16), sD = __shfl_up(iD, 16);
        if (c >= 1) { iN += sN; iD += sD; }
        sN = __shfl_up(iN, 32); sD = __shfl_up(iD, 32);
        if (c >= 2) { iN += sN; iD += sD; }
    }
    float num = iN - lN;    // exclusive prefix of cumsum(J*t)
    float den = iD - lD;    // exclusive prefix of cumsum(J)

    const int kbeg = c * 36;
    uint32_t ecur = skey[kbeg];
    float tbound = __shfl_down((float)(ecur >> 8) * INV23, 16);
    if (c == 3) tbound = 1.0e6f;

    // pass B: first-valid select within chunk
    float sN2 = 0.0f, sD2 = 1.0f;
    bool  found = false;
    #pragma unroll 1
    for (int i = 0; i < 36; ++i) {
        uint32_t enext = 0; float tn;
        if (i < 35) { enext = skey[kbeg + i + 1]; tn = (float)(enext >> 8) * INV23; }
        else        { tn = tbound; }
        const float t = (float)(ecur >> 8) * INV23;
        const float w = kern[(ecur & 255u) * FT + f];
        num = fmaf(w, t, num);
        den += w;
        const float numt = num + thr;
        const float dena = den + al;
        const bool valid = (dena > 0.0f) && (numt < tn * dena);
        const bool take  = !found && (valid || (c == 0 && i == 0));
        if (take) { sN2 = numt; sD2 = dena; }
        found = found || valid;
        if (i < 35) ecur = enext;
    }
    int pos = found ? c : ((c == 0) ? 6 : 7);
    {
        int   opos = __shfl_xor(pos, 16);
        float oN   = __shfl_xor(sN2, 16);
        float oD   = __shfl_xor(sD2, 16);
        if (opos < pos) { pos = opos; sN2 = oN; sD2 = oD; }
        opos = __shfl_xor(pos, 32);
        oN   = __shfl_xor(sN2, 32);
        oD   = __shfl_xor(sD2, 32);
        if (opos < pos) { pos = opos; sN2 = oN; sD2 = oD; }
    }
    if (c == 0) {
        const float ti = sN2 / sD2;
        out[n * FT + f] = (ti < 1.0f) ? ti : 1.0f;   // clamp to T_MAX
    }
}

// Hot kernel: one wave = one interior pixel, ~100 instructions, zero LDS ops.
// 32-bit keys: t = m*2^-23 exactly (jax.random.uniform), key=(m<<8)|k ->
// u32 order == stable argsort. First sorted candidate = wave-min key,
// validated with the exact reference condition; border / any-zero / failed
// validation -> wave-uniform call into cold_pixel.
__global__ __launch_bounds__(THREADS) void spiking_conv2d_kernel(
    const float* __restrict__ tj,        // [B,56,56,16]
    const float* __restrict__ kern,      // [3,3,16,16] flat [144][16]
    const float* __restrict__ threshold, // [16]
    const float* __restrict__ alpha,     // [16]
    float* __restrict__ out,             // [B,56,56,16]
    int npix)
{
    __shared__ uint32_t sKey[WAVES][KPW];   // cold-path scratch, 2560 B

    const int tid  = threadIdx.x;
    const int wave = tid >> 6;
    const int lane = tid & 63;
    const int f    = lane & 15;             // channel / feature
    const int c    = lane >> 4;             // tap group

    const int n = blockIdx.x * WAVES + wave;
    if (n >= npix) return;

    const float thr = threshold[f];
    const float al  = alpha[f];

    const int hw  = HT * WD;
    const int bb  = n / hw;
    const int rem = n - bb * hw;
    const int y   = rem / WD;
    const int x   = rem - y * WD;

    if (y == 0 || y == HT - 1 || x == 0 || x == WD - 1) {
        cold_pixel(tj, kern, thr, al, out, n, &sKey[wave][0]);
        return;
    }

    // interior: unchecked loads. lane's taps: c, c+4, (8 if lane<16); channel f.
    const int base = (bb * hw + (y - 1) * WD + (x - 1)) * CH + f;
    const int j0 = c, j1 = c + 4;
    const int off0 = ((j0 / 3) * WD + (j0 % 3)) * CH;
    const int off1 = ((j1 / 3) * WD + (j1 % 3)) * CH;
    const int off2 = (2 * WD + 2) * CH;
    const float ta  = tj[base + off0];
    const float tb  = tj[base + off1];
    const float tcv = (lane < 16) ? tj[base + off2] : 1.0f;

    const uint32_t ma = (uint32_t)(ta * 8388608.0f);    // exact
    const uint32_t mb = (uint32_t)(tb * 8388608.0f);
    const uint32_t mc = (uint32_t)(tcv * 8388608.0f);
    const uint32_t key0 = (ma << 8) | (uint32_t)lane;
    const uint32_t key1 = (mb << 8) | (uint32_t)(lane + 64);
    const uint32_t key2 = (lane < 16) ? ((mc << 8) | (uint32_t)(lane + 128))
                                      : 0xFFFFFFFFu;

    const bool anyz = (ma == 0u) || (mb == 0u) || ((lane < 16) && (mc == 0u));
    if (__any(anyz)) {
        cold_pixel(tj, kern, thr, al, out, n, &sKey[wave][0]);
        return;
    }

    // two-min butterfly over all 144 keys (dummy key2 = 0xFFFFFFFF is inert)
    const uint32_t lo = min(key0, key1), hi = max(key0, key1);
    uint32_t m1 = min(lo, key2);
    uint32_t m2 = min(hi, max(lo, key2));
    #pragma unroll
    for (int s = 1; s < 64; s <<= 1) {
        const uint32_t o1 = (uint32_t)__shfl_xor((int)m1, s);
        const uint32_t o2 = (uint32_t)__shfl_xor((int)m2, s);
        const uint32_t nl = min(m1, o1);
        const uint32_t nh = max(m1, o1);
        m2 = min(min(nh, m2), o2);
        m1 = nl;
    }

    // candidate at sorted position 0 (= wave-min key); exact validation
    const float t1 = (float)(m1 >> 8) * INV23;
    const float t2 = (float)(m2 >> 8) * INV23;
    const float w  = kern[(m1 & 255u) * FT + f];    // wave-uniform row
    const float selN = fmaf(w, t1, thr);            // + alpha*T_MIN_PREV (=0)
    const float selD = w + al;
    const bool ok = (selD > 0.0f) && (selN < t2 * selD);

    if (!__all(ok)) {
        cold_pixel(tj, kern, thr, al, out, n, &sKey[wave][0]);
        return;
    }
    if (lane < 16) {
        const float ti = selN / selD;
        out[n * FT + f] = (ti < 1.0f) ? ti : 1.0f;  // clamp to T_MAX
    }
}

extern "C" void kernel_launch(void* const* d_in, const int* in_sizes, int n_in,
                              void* d_out, int out_size, void* d_ws, size_t ws_size,
                              hipStream_t stream) {
    const float* tj    = (const float*)d_in[0];
    const float* kern  = (const float*)d_in[1];
    const float* thr   = (const float*)d_in[2];
    const float* alpha = (const float*)d_in[3];
    float*       out   = (float*)d_out;

    const int npix   = in_sizes[0] / CH;                  // B*H*W = 12544
    const int blocks = (npix + WAVES - 1) / WAVES;        // 3136
    spiking_conv2d_kernel<<<blocks, THREADS, 0, stream>>>(tj, kern, thr, alpha, out, npix);
}